// Round 11
// baseline (92.551 us; speedup 1.0000x reference)
//
#include <hip/hip_runtime.h>

#define EPSV 1e-5f
constexpr int NPTS  = 16384;
constexpr int MGRID = 65536;
constexpr int ZD = 11, YD = 200, XD = 176;
constexpr int NVOX = 2 * ZD * YD * XD;          // 774400
constexpr int NB_VM = (NVOX / 8 + 255) / 256;   // 379 blocks for vm16 compress

typedef _Float16 h2  __attribute__((ext_vector_type(2)));
typedef _Float16 h8v __attribute__((ext_vector_type(8)));
struct alignas(16) H8 { h2 a, b, c, d; };       // 8 fp16 channels

#if __has_builtin(__builtin_amdgcn_fdot2)
#define FDOT2(a, b, c) __builtin_amdgcn_fdot2((a), (b), (c), false)
#else
#define FDOT2(a, b, c) ((c) + (float)(a).x * (float)(b).x + (float)(a).y * (float)(b).y)
#endif

// ---------------------------------------------------------------------------
// ws layout (bytes):
//   0          ss_in  : float[2][{scale,shift}][32]        (512 B)
//   4096       ss_out : float[2][{scale,shift}][64]        (1 KB)
//   8192       pIn    : float[2][256][64]                  (128 KB)
//   139264     fraw_h : _Float16[2][16385][32] raw, row0=pad (2 MB)
//   2236544    pf     : float[8+64][32]                    (9216 B)
//   2245760    vm16   : short[774400]                      (1.5 MB)
//   3794560    nf_h   : _Float16[2][65536][32]             (8.4 MB)
//   12183168   pOut   : float[2][512][128]                 (512 KB)
//   12707840   psum0_h: _Float16[8][32]                    (512 B)
//   12708352   psum1_h: _Float16[64][32]                   (4 KB)
// ---------------------------------------------------------------------------

__device__ __forceinline__ h8v gload_h8(const _Float16* p) {
    h8v r;
    asm volatile("global_load_dwordx4 %0, %1, off" : "=v"(r) : "v"(p));
    return r;
}
__device__ __forceinline__ uint4 gload_u128(const void* p) {
    uint4 r;
    asm volatile("global_load_dwordx4 %0, %1, off" : "=v"(r) : "v"(p));
    return r;
}
__device__ __forceinline__ void vm_wait0() {
    asm volatile("s_waitcnt vmcnt(0)" ::: "memory");
    __builtin_amdgcn_sched_barrier(0);   // rule #18: keep reg-only ops below
}
__device__ __forceinline__ h8v zero8() {
    h8v z;
#pragma unroll
    for (int i = 0; i < 8; ++i) z[i] = (_Float16)0.f;
    return z;
}
__device__ __forceinline__ h8v shfl_xor_h8(h8v v, int m) {
    union { h8v h; int4 i; } u; u.h = v;
    u.i.x = __shfl_xor(u.i.x, m, 64);
    u.i.y = __shfl_xor(u.i.y, m, 64);
    u.i.z = __shfl_xor(u.i.z, m, 64);
    u.i.w = __shfl_xor(u.i.w, m, 64);
    return u.h;
}

// L1: fused prelude — vm16 compress | fin matmul (raw fp16 + stats partials) | pf
__global__ __launch_bounds__(256) void k_pre(
    const int* __restrict__ vm, const float* __restrict__ features,
    const float* __restrict__ Win, const float* __restrict__ Wpos,
    const float* __restrict__ g_pos, const float* __restrict__ b_pos,
    short* __restrict__ vm16, _Float16* __restrict__ fraw_h,
    float* __restrict__ pIn, float* __restrict__ pf)
{
    __shared__ float smem[2688];
    int bid = blockIdx.x, t = threadIdx.x;

    if (bid < NB_VM) {                       // ---- vm -> int16 (8 ints/thread)
        int i = bid * 256 + t;
        if (i < NVOX / 8) {
            int4 v0 = ((const int4*)vm)[i * 2];
            int4 v1 = ((const int4*)vm)[i * 2 + 1];
            uint4 o;
            o.x = (v0.x & 0xffff) | (v0.y << 16);
            o.y = (v0.z & 0xffff) | (v0.w << 16);
            o.z = (v1.x & 0xffff) | (v1.y << 16);
            o.w = (v1.z & 0xffff) | (v1.w << 16);
            ((uint4*)vm16)[i] = o;
        }
        return;
    }
    if (bid < NB_VM + 512) {                 // ---- fin: raw y fp16 + partials
        int b2 = bid - NB_VM;
        int k = b2 >> 8, bx = b2 & 255;
        float* Wls = smem;                   // [32][68]
        float* s_  = smem + 2176;
        float* q_  = smem + 2432;
        for (int idx = t; idx < 2048; idx += 256)
            Wls[(idx >> 6) * 68 + (idx & 63)] = Win[k * 2048 + idx];
        __syncthreads();
        int c = t & 31, g = t >> 5;
        float w[64];
#pragma unroll
        for (int i4 = 0; i4 < 16; ++i4) {
            float4 wv = *(const float4*)&Wls[c * 68 + i4 * 4];
            w[i4 * 4] = wv.x; w[i4 * 4 + 1] = wv.y; w[i4 * 4 + 2] = wv.z; w[i4 * 4 + 3] = wv.w;
        }
        int base = bx * 64;
        float ssum = 0.f, ssq = 0.f;
        for (int it = 0; it < 8; ++it) {
            int pt = base + it * 8 + g;
            const float4* fr = (const float4*)(features + (size_t)pt * 64);
            float y = 0.f;
#pragma unroll
            for (int i4 = 0; i4 < 16; ++i4) {
                float4 v = fr[i4];
                y += v.x * w[i4 * 4] + v.y * w[i4 * 4 + 1] + v.z * w[i4 * 4 + 2] + v.w * w[i4 * 4 + 3];
            }
            fraw_h[((size_t)k * (NPTS + 1) + pt + 1) * 32 + c] = (_Float16)y;
            ssum += y; ssq += y * y;
        }
        s_[t] = ssum; q_[t] = ssq;
        __syncthreads();
        if (t < 32) {
            float fs = 0.f, fq = 0.f;
#pragma unroll
            for (int gg = 0; gg < 8; ++gg) { fs += s_[gg * 32 + t]; fq += q_[gg * 32 + t]; }
            float* pb = pIn + ((size_t)k * 256 + bx) * 64;
            pb[t] = fs; pb[32 + t] = fq;
        }
        return;
    }
    // ---- pf: BN over offsets of off_xyz @ W_pos^T (f32, 1 block)
    float* praw = smem;
    int pfoff = 0;
    for (int k = 0; k < 2; ++k) {
        int r = k + 1, s = 2 * r, noff = s * s * s;
        for (int idx = t; idx < noff * 32; idx += 256) {
            int j = idx >> 5, c = idx & 31;
            int xi = j % s, yi = (j / s) % s, zi = j / (s * s);
            const float* W = Wpos + (k * 32 + c) * 3;
            praw[idx] = (float)(xi - r) * W[0] + (float)(yi - r) * W[1] + (float)(zi - r) * W[2];
        }
        __syncthreads();
        if (t < 32) {
            float sum = 0.f, sq = 0.f;
            for (int j = 0; j < noff; ++j) { float v = praw[j * 32 + t]; sum += v; sq += v * v; }
            float mu  = sum / (float)noff;
            float var = fmaxf(sq / (float)noff - mu * mu, 0.f);
            float rs  = rsqrtf(var + EPSV);
            float g = g_pos[k * 32 + t], b = b_pos[k * 32 + t];
            for (int j = 0; j < noff; ++j)
                pf[pfoff + j * 32 + t] = (praw[j * 32 + t] - mu) * rs * g + b;
        }
        __syncthreads();
        pfoff += noff * 32;
    }
}

// L2: reduce pIn -> scale/shift ; write pad row ; precompute fp16 psum tables
__global__ __launch_bounds__(256) void k_reduce_in(
    const float* __restrict__ pIn, const float* __restrict__ g_in,
    const float* __restrict__ b_in, const float* __restrict__ pf,
    float* __restrict__ ss_in, _Float16* __restrict__ fraw_h,
    _Float16* __restrict__ psum0_h, _Float16* __restrict__ psum1_h)
{
    __shared__ float ss[256], qq[256];
    __shared__ float sh_shift;
    int b = blockIdx.x;          // 64 blocks: k = b>>5, c = b&31
    int k = b >> 5, c = b & 31;
    int t = threadIdx.x;
    ss[t] = pIn[((size_t)k * 256 + t) * 64 + c];
    qq[t] = pIn[((size_t)k * 256 + t) * 64 + 32 + c];
    __syncthreads();
    if (t < 128) { ss[t] += ss[t + 128]; qq[t] += qq[t + 128]; } __syncthreads();
    if (t < 64)  { ss[t] += ss[t + 64];  qq[t] += qq[t + 64];  } __syncthreads();
    if (t < 32)  { ss[t] += ss[t + 32];  qq[t] += qq[t + 32];  } __syncthreads();
    if (t == 0) {
        float sv = 0.f, sq = 0.f;
#pragma unroll
        for (int i = 0; i < 32; ++i) { sv += ss[i]; sq += qq[i]; }
        float mu  = sv / (float)NPTS;
        float var = fmaxf(sq / (float)NPTS - mu * mu, 0.f);
        float rs  = rsqrtf(var + EPSV);
        float scale = g_in[k * 32 + c] * rs;
        float shift = b_in[k * 32 + c] - mu * scale;
        ss_in[k * 64 + c]      = scale;
        ss_in[k * 64 + 32 + c] = shift;
        float pad = (scale != 0.f) ? (-shift / scale) : 0.f;
        pad = fminf(fmaxf(pad, -60000.f), 60000.f);
        fraw_h[(size_t)k * (NPTS + 1) * 32 + c] = (_Float16)pad;   // row 0
        sh_shift = shift;
    }
    __syncthreads();
    float shift = sh_shift;
    if (k == 1) {
        if (t < 64) psum1_h[t * 32 + c] = (_Float16)(pf[256 + t * 32 + c] + shift);
    } else {
        if (t < 8)  psum0_h[t * 32 + c] = (_Float16)(pf[t * 32 + c] + shift);
    }
}

// L3: LEAN gather (BOTH k) + relu-max. No LDS, no barrier.
// 256 threads = 16 points x (4 jg x 4 chan-chunks). 4 packed vm loads/lane;
// k=0 pack rows reused from sibling jg lanes via shfl. psum read from
// L1-resident precomputed fp16 global tables.
__global__ __launch_bounds__(256) void k_gather(
    const int* __restrict__ nc, const short* __restrict__ vm16,
    const _Float16* __restrict__ fraw_h,
    const _Float16* __restrict__ psum0_h, const _Float16* __restrict__ psum1_h,
    const float* __restrict__ ss_in, _Float16* __restrict__ nf_h)
{
    int t = threadIdx.x, bx = blockIdx.x;
    int c4 = t & 3, jg = (t >> 2) & 3, lp = t >> 4;
    int pt = bx * 16 + lp;

    // ---- coords + packed vm addresses (consume cc BEFORE any asm load)
    int4 cc = ((const int4*)nc)[pt];
    int bb = cc.x, xc = cc.y, yc = cc.z, zc = cc.w;
    // reference quirk: fastest mesh idx -> z coord, slowest -> x coord
    int Zo[4];
#pragma unroll
    for (int u = 0; u < 4; ++u) {
        int zq = min(max(zc + u - 2, 0), ZD - 1);
        Zo[u] = (bb * ZD + zq) * (YD * XD);
    }
    int Yo1 = min(max(yc + jg - 2, 0), YD - 1) * XD;
    int ax1 = (min(max(xc - 2, 0), XD - 4)) & ~1;       // pack base (even)
    int Xoff[4];
#pragma unroll
    for (int a = 0; a < 4; ++a)
        Xoff[a] = min(max(xc - 2 + a, 0), XD - 1) - ax1;   // in [0,4]
    int x0a = min(max(xc - 1, 0), XD - 1);
    int x0b = min(max(xc, 0), XD - 1);
    int pos0a = x0a - ax1, pos0b = x0b - ax1;           // provably in [0,3]
    __builtin_amdgcn_sched_barrier(0);

    // ---- phase A: 4 packed vm loads in flight
    uint4 pk[4];
#pragma unroll
    for (int u = 0; u < 4; ++u)
        pk[u] = gload_u128(vm16 + Zo[u] + Yo1 + ax1);
    vm_wait0();                          // packs ready

    // ---- k=0 pack rows from sibling jg lanes (y rows jg'=1,2; z rows u=1,2)
    int sl = ((t & 63) & ~12) | ((((jg >> 1) & 1) + 1) << 2);
    int p1x = __shfl((int)pk[1].x, sl, 64);
    int p1y = __shfl((int)pk[1].y, sl, 64);
    int p2x = __shfl((int)pk[2].x, sl, 64);
    int p2y = __shfl((int)pk[2].y, sl, 64);
    unsigned long long sel64 = (jg & 1)
        ? ((unsigned long long)(unsigned)p2x | ((unsigned long long)(unsigned)p2y << 32))
        : ((unsigned long long)(unsigned)p1x | ((unsigned long long)(unsigned)p1y << 32));
    unsigned r0 = ((unsigned)(sel64 >> (pos0a * 16)) + 1) & 0xFFFFu;
    unsigned r1 = ((unsigned)(sel64 >> (pos0b * 16)) + 1) & 0xFFFFu;

    // ---- phase B: 18 row gathers in flight
    const _Float16* fr1 = fraw_h + (size_t)(NPTS + 1) * 32;
    h8v g1[16], g0[2];
#pragma unroll
    for (int u = 0; u < 4; ++u) {
        unsigned long long lo = (unsigned long long)pk[u].x | ((unsigned long long)pk[u].y << 32);
        unsigned long long hi = (unsigned long long)pk[u].z | ((unsigned long long)pk[u].w << 32);
#pragma unroll
        for (int a = 0; a < 4; ++a) {
            int off = Xoff[a];
            unsigned long long sel = (off & 4) ? hi : lo;
            unsigned row = ((unsigned)(sel >> ((off & 3) * 16)) + 1) & 0xFFFFu;  // -1 -> pad row 0
            g1[u * 4 + a] = gload_h8(fr1 + (size_t)row * 32 + c4 * 8);
        }
    }
    g0[0] = gload_h8(fraw_h + (size_t)r0 * 32 + c4 * 8);
    g0[1] = gload_h8(fraw_h + (size_t)r1 * 32 + c4 * 8);
    vm_wait0();                          // rows ready

    // ---- phase C: scale + add(psum) + relu-max (relu folds into max)
    h8v sc1v, sc0v;
#pragma unroll
    for (int i = 0; i < 8; ++i) {
        sc1v[i] = (_Float16)ss_in[64 + c4 * 8 + i];
        sc0v[i] = (_Float16)ss_in[c4 * 8 + i];
    }
    h8v acc1 = zero8(), acc0 = zero8();
#pragma unroll
    for (int i = 0; i < 16; ++i) {
        int o = (i & 3) * 16 + jg * 4 + (i >> 2);
        h8v pv = *(const h8v*)(psum1_h + o * 32 + c4 * 8);
        acc1 = __builtin_elementwise_max(acc1, g1[i] * sc1v + pv);
    }
    {
        h8v pv = *(const h8v*)(psum0_h + jg * 32 + c4 * 8);
        acc0 = __builtin_elementwise_max(acc0, g0[0] * sc0v + pv);
        h8v pv2 = *(const h8v*)(psum0_h + (4 + jg) * 32 + c4 * 8);
        acc0 = __builtin_elementwise_max(acc0, g0[1] * sc0v + pv2);
    }
    acc1 = __builtin_elementwise_max(acc1, shfl_xor_h8(acc1, 4));
    acc1 = __builtin_elementwise_max(acc1, shfl_xor_h8(acc1, 8));
    acc0 = __builtin_elementwise_max(acc0, shfl_xor_h8(acc0, 4));
    acc0 = __builtin_elementwise_max(acc0, shfl_xor_h8(acc0, 8));
    if (jg == 0) {
        *(h8v*)(nf_h + ((size_t)MGRID + pt) * 32 + c4 * 8) = acc1;   // k=1
        *(h8v*)(nf_h + (size_t)pt * 32 + c4 * 8) = acc0;             // k=0
    }
}

// L4: out-matmul stats partials; 128 points/block, grid (512, 2)
__global__ __launch_bounds__(256) void k_out_stats(
    const _Float16* __restrict__ nf_h, const float* __restrict__ Wout,
    float* __restrict__ pOut)
{
    __shared__ __align__(16) _Float16 nfs[128 * 32];   // 8 KB
    __shared__ h2 Wh[64 * 17];                          // 4.3 KB
    __shared__ float s_[256], q_[256];
    int k = blockIdx.y, t = threadIdx.x, bx = blockIdx.x;
    const _Float16* src = nf_h + ((size_t)k * MGRID + (size_t)bx * 128) * 32;
    ((uint4*)nfs)[t]       = ((const uint4*)src)[t];
    ((uint4*)nfs)[256 + t] = ((const uint4*)src)[256 + t];
    for (int i = t; i < 1024; i += 256) {
        int c = i >> 4, q = i & 15;
        h2 v;
        v.x = (_Float16)Wout[k * 2048 + c * 32 + 2 * q];
        v.y = (_Float16)Wout[k * 2048 + c * 32 + 2 * q + 1];
        Wh[c * 17 + q] = v;
    }
    __syncthreads();
    int c = t & 63, pg = t >> 6;
    h2 w[16];
#pragma unroll
    for (int i = 0; i < 16; ++i) w[i] = Wh[c * 17 + i];
    float sum = 0.f, sq = 0.f;
    for (int i = 0; i < 32; ++i) {
        const h2* row = (const h2*)(nfs + (pg * 32 + i) * 32);
        float y = 0.f;
#pragma unroll
        for (int iq = 0; iq < 16; ++iq) y = FDOT2(row[iq], w[iq], y);
        sum += y; sq += y * y;
    }
    s_[t] = sum; q_[t] = sq;
    __syncthreads();
    if (t < 128) { s_[t] += s_[t + 128]; q_[t] += q_[t + 128]; }
    __syncthreads();
    if (t < 64) {
        pOut[((size_t)k * 512 + bx) * 128 + t]      = s_[t] + s_[t + 64];
        pOut[((size_t)k * 512 + bx) * 128 + 64 + t] = q_[t] + q_[t + 64];
    }
}

// L5: parallel reduce pOut -> scale/shift ; one block per (k, c)
__global__ __launch_bounds__(256) void k_out_reduce(
    const float* __restrict__ pOut, const float* __restrict__ g_out,
    const float* __restrict__ b_out, float* __restrict__ ss_out)
{
    __shared__ float ss[256], qq[256];
    int b = blockIdx.x;          // 128 blocks: k = b>>6, c = b&63
    int k = b >> 6, c = b & 63;
    int t = threadIdx.x;
    float sv = 0.f, sq = 0.f;
#pragma unroll
    for (int i = 0; i < 2; ++i) {
        size_t row = (size_t)k * 512 + t + i * 256;
        sv += pOut[row * 128 + c];
        sq += pOut[row * 128 + 64 + c];
    }
    ss[t] = sv; qq[t] = sq;
    __syncthreads();
    if (t < 128) { ss[t] += ss[t + 128]; qq[t] += qq[t + 128]; } __syncthreads();
    if (t < 64)  { ss[t] += ss[t + 64];  qq[t] += qq[t + 64];  } __syncthreads();
    if (t < 32)  { ss[t] += ss[t + 32];  qq[t] += qq[t + 32];  } __syncthreads();
    if (t == 0) {
        float fs = 0.f, fq = 0.f;
#pragma unroll
        for (int i = 0; i < 32; ++i) { fs += ss[i]; fq += qq[i]; }
        float mu  = fs / (float)MGRID;
        float var = fmaxf(fq / (float)MGRID - mu * mu, 0.f);
        float rs  = rsqrtf(var + EPSV);
        float scale = g_out[k * 64 + c] * rs;
        float shift = b_out[k * 64 + c] - mu * scale;
        ss_out[k * 128 + c]      = scale;
        ss_out[k * 128 + 64 + c] = shift;
    }
}

// L6: out[:, k*64+c] = relu(y*scale + shift), dot2 matmul
__global__ __launch_bounds__(256) void k_out_write(
    const _Float16* __restrict__ nf_h, const float* __restrict__ Wout,
    const float* __restrict__ ss_out, float* __restrict__ out)
{
    __shared__ h2 Wh[64 * 17];
    int k = blockIdx.y, t = threadIdx.x;
    for (int i = t; i < 1024; i += 256) {
        int c = i >> 4, q = i & 15;
        h2 v;
        v.x = (_Float16)Wout[k * 2048 + c * 32 + 2 * q];
        v.y = (_Float16)Wout[k * 2048 + c * 32 + 2 * q + 1];
        Wh[c * 17 + q] = v;
    }
    __syncthreads();
    int c = t & 63, pl = t >> 6;
    float scale = ss_out[k * 128 + c], shift = ss_out[k * 128 + 64 + c];
    const h2* w = &Wh[c * 17];
    int base = blockIdx.x * 64;
    for (int it = 0; it < 16; ++it) {
        int pt = base + it * 4 + pl;
        const H8* row = (const H8*)(nf_h + ((size_t)k * MGRID + pt) * 32);
        H8 r0 = row[0], r1 = row[1], r2 = row[2], r3 = row[3];
        h2 hh[16] = {r0.a, r0.b, r0.c, r0.d, r1.a, r1.b, r1.c, r1.d,
                     r2.a, r2.b, r2.c, r2.d, r3.a, r3.b, r3.c, r3.d};
        float y = 0.f;
#pragma unroll
        for (int iq = 0; iq < 16; ++iq) y = FDOT2(hh[iq], w[iq], y);
        float o = y * scale + shift;
        out[(size_t)pt * 128 + k * 64 + c] = o > 0.f ? o : 0.f;
    }
}

extern "C" void kernel_launch(void* const* d_in, const int* in_sizes, int n_in,
                              void* d_out, int out_size, void* d_ws, size_t ws_size,
                              hipStream_t stream) {
    const int*   new_coords = (const int*)d_in[4];
    const float* features   = (const float*)d_in[5];
    const int*   vm         = (const int*)d_in[6];
    const float* W_in  = (const float*)d_in[7];
    const float* g_in  = (const float*)d_in[8];
    const float* b_in  = (const float*)d_in[9];
    const float* W_pos = (const float*)d_in[10];
    const float* g_pos = (const float*)d_in[11];
    const float* b_pos = (const float*)d_in[12];
    const float* W_out = (const float*)d_in[13];
    const float* g_out = (const float*)d_in[14];
    const float* b_out = (const float*)d_in[15];
    float* out = (float*)d_out;

    char* ws = (char*)d_ws;
    float*     ss_in   = (float*)(ws);
    float*     ss_out  = (float*)(ws + 4096);
    float*     pIn     = (float*)(ws + 8192);
    _Float16*  fraw_h  = (_Float16*)(ws + 139264);
    float*     pf      = (float*)(ws + 2236544);
    short*     vm16    = (short*)(ws + 2245760);
    _Float16*  nf_h    = (_Float16*)(ws + 3794560);
    float*     pOut    = (float*)(ws + 12183168);
    _Float16*  psum0_h = (_Float16*)(ws + 12707840);
    _Float16*  psum1_h = (_Float16*)(ws + 12708352);

    k_pre<<<NB_VM + 512 + 1, 256, 0, stream>>>(vm, features, W_in, W_pos, g_pos, b_pos,
                                               vm16, fraw_h, pIn, pf);
    k_reduce_in<<<64, 256, 0, stream>>>(pIn, g_in, b_in, pf, ss_in, fraw_h,
                                        psum0_h, psum1_h);

    k_gather<<<MGRID / 16, 256, 0, stream>>>(new_coords, vm16, fraw_h,
                                             psum0_h, psum1_h, ss_in, nf_h);

    dim3 gS(512, 2);
    k_out_stats<<<gS, 256, 0, stream>>>(nf_h, W_out, pOut);

    k_out_reduce<<<128, 256, 0, stream>>>(pOut, g_out, b_out, ss_out);

    dim3 gW(MGRID / 64, 2);
    k_out_write<<<gW, 256, 0, stream>>>(nf_h, W_out, ss_out, out);
}

// Round 12
// 87.963 us; speedup vs baseline: 1.0522x; 1.0522x over previous
//
#include <hip/hip_runtime.h>

#define EPSV 1e-5f
constexpr int NPTS  = 16384;
constexpr int MGRID = 65536;
constexpr int ZD = 11, YD = 200, XD = 176;
constexpr int NVOX = 2 * ZD * YD * XD;          // 774400
constexpr int NB_VM = (NVOX / 8 + 255) / 256;   // 379 blocks for vm16 compress

typedef _Float16 h2  __attribute__((ext_vector_type(2)));
typedef _Float16 h8v __attribute__((ext_vector_type(8)));
struct alignas(16) H8 { h2 a, b, c, d; };       // 8 fp16 channels

#if __has_builtin(__builtin_amdgcn_fdot2)
#define FDOT2(a, b, c) __builtin_amdgcn_fdot2((a), (b), (c), false)
#else
#define FDOT2(a, b, c) ((c) + (float)(a).x * (float)(b).x + (float)(a).y * (float)(b).y)
#endif

// counted VMEM wait + scheduler fence (rule #18)
#define VM_WAIT(N) do { asm volatile("s_waitcnt vmcnt(" #N ")" ::: "memory"); \
                        __builtin_amdgcn_sched_barrier(0); } while (0)

// ---------------------------------------------------------------------------
// ws layout (bytes):
//   0          ss_in  : float[2][{scale,shift}][32]        (512 B)
//   4096       ss_out : float[2][{scale,shift}][64]        (1 KB)
//   8192       pIn    : float[2][256][64]                  (128 KB)
//   139264     fraw_h : _Float16[2][16385][32] raw, row0=pad (2 MB)
//   2236544    pf     : float[8+64][32]                    (9216 B)
//   2245760    vm16   : short[774400]  (values BIASED +1: 0 = empty) (1.5 MB)
//   3794560    nf_h   : _Float16[2][65536][32]             (8.4 MB)
//   12183168   pOut   : float[2][512][128]                 (512 KB)
// ---------------------------------------------------------------------------

__device__ __forceinline__ h8v gload_h8(const _Float16* p) {
    h8v r;
    asm volatile("global_load_dwordx4 %0, %1, off" : "=v"(r) : "v"(p));
    return r;
}
__device__ __forceinline__ uint4 gload_u128(const void* p) {
    uint4 r;
    asm volatile("global_load_dwordx4 %0, %1, off" : "=v"(r) : "v"(p));
    return r;
}
__device__ __forceinline__ uint2 gload_u64(const void* p) {
    uint2 r;
    asm volatile("global_load_dwordx2 %0, %1, off" : "=v"(r) : "v"(p));
    return r;
}
__device__ __forceinline__ h8v zero8() {
    h8v z;
#pragma unroll
    for (int i = 0; i < 8; ++i) z[i] = (_Float16)0.f;
    return z;
}
__device__ __forceinline__ h8v shfl_xor_h8(h8v v, int m) {
    union { h8v h; int4 i; } u; u.h = v;
    u.i.x = __shfl_xor(u.i.x, m, 64);
    u.i.y = __shfl_xor(u.i.y, m, 64);
    u.i.z = __shfl_xor(u.i.z, m, 64);
    u.i.w = __shfl_xor(u.i.w, m, 64);
    return u.h;
}

// L1: fused prelude — vm16 compress (+1 bias) | fin matmul | pf
__global__ __launch_bounds__(256) void k_pre(
    const int* __restrict__ vm, const float* __restrict__ features,
    const float* __restrict__ Win, const float* __restrict__ Wpos,
    const float* __restrict__ g_pos, const float* __restrict__ b_pos,
    short* __restrict__ vm16, _Float16* __restrict__ fraw_h,
    float* __restrict__ pIn, float* __restrict__ pf)
{
    __shared__ float smem[2688];
    int bid = blockIdx.x, t = threadIdx.x;

    if (bid < NB_VM) {                       // ---- vm -> int16+1 (8 ints/thread)
        int i = bid * 256 + t;
        if (i < NVOX / 8) {
            int4 v0 = ((const int4*)vm)[i * 2];
            int4 v1 = ((const int4*)vm)[i * 2 + 1];
            uint4 o;
            o.x = ((v0.x + 1) & 0xffff) | ((v0.y + 1) << 16);
            o.y = ((v0.z + 1) & 0xffff) | ((v0.w + 1) << 16);
            o.z = ((v1.x + 1) & 0xffff) | ((v1.y + 1) << 16);
            o.w = ((v1.z + 1) & 0xffff) | ((v1.w + 1) << 16);
            ((uint4*)vm16)[i] = o;
        }
        return;
    }
    if (bid < NB_VM + 512) {                 // ---- fin: raw y fp16 + partials
        int b2 = bid - NB_VM;
        int k = b2 >> 8, bx = b2 & 255;
        float* Wls = smem;                   // [32][68]
        float* s_  = smem + 2176;
        float* q_  = smem + 2432;
        for (int idx = t; idx < 2048; idx += 256)
            Wls[(idx >> 6) * 68 + (idx & 63)] = Win[k * 2048 + idx];
        __syncthreads();
        int c = t & 31, g = t >> 5;
        float w[64];
#pragma unroll
        for (int i4 = 0; i4 < 16; ++i4) {
            float4 wv = *(const float4*)&Wls[c * 68 + i4 * 4];
            w[i4 * 4] = wv.x; w[i4 * 4 + 1] = wv.y; w[i4 * 4 + 2] = wv.z; w[i4 * 4 + 3] = wv.w;
        }
        int base = bx * 64;
        float ssum = 0.f, ssq = 0.f;
        for (int it = 0; it < 8; ++it) {
            int pt = base + it * 8 + g;
            const float4* fr = (const float4*)(features + (size_t)pt * 64);
            float y = 0.f;
#pragma unroll
            for (int i4 = 0; i4 < 16; ++i4) {
                float4 v = fr[i4];
                y += v.x * w[i4 * 4] + v.y * w[i4 * 4 + 1] + v.z * w[i4 * 4 + 2] + v.w * w[i4 * 4 + 3];
            }
            fraw_h[((size_t)k * (NPTS + 1) + pt + 1) * 32 + c] = (_Float16)y;
            ssum += y; ssq += y * y;
        }
        s_[t] = ssum; q_[t] = ssq;
        __syncthreads();
        if (t < 32) {
            float fs = 0.f, fq = 0.f;
#pragma unroll
            for (int gg = 0; gg < 8; ++gg) { fs += s_[gg * 32 + t]; fq += q_[gg * 32 + t]; }
            float* pb = pIn + ((size_t)k * 256 + bx) * 64;
            pb[t] = fs; pb[32 + t] = fq;
        }
        return;
    }
    // ---- pf: BN over offsets of off_xyz @ W_pos^T (f32, 1 block)
    float* praw = smem;
    int pfoff = 0;
    for (int k = 0; k < 2; ++k) {
        int r = k + 1, s = 2 * r, noff = s * s * s;
        for (int idx = t; idx < noff * 32; idx += 256) {
            int j = idx >> 5, c = idx & 31;
            int xi = j % s, yi = (j / s) % s, zi = j / (s * s);
            const float* W = Wpos + (k * 32 + c) * 3;
            praw[idx] = (float)(xi - r) * W[0] + (float)(yi - r) * W[1] + (float)(zi - r) * W[2];
        }
        __syncthreads();
        if (t < 32) {
            float sum = 0.f, sq = 0.f;
            for (int j = 0; j < noff; ++j) { float v = praw[j * 32 + t]; sum += v; sq += v * v; }
            float mu  = sum / (float)noff;
            float var = fmaxf(sq / (float)noff - mu * mu, 0.f);
            float rs  = rsqrtf(var + EPSV);
            float g = g_pos[k * 32 + t], b = b_pos[k * 32 + t];
            for (int j = 0; j < noff; ++j)
                pf[pfoff + j * 32 + t] = (praw[j * 32 + t] - mu) * rs * g + b;
        }
        __syncthreads();
        pfoff += noff * 32;
    }
}

// L2: parallel reduce pIn -> scale/shift ; one block per (k, c)
__global__ __launch_bounds__(256) void k_reduce_in(
    const float* __restrict__ pIn, const float* __restrict__ g_in,
    const float* __restrict__ b_in, float* __restrict__ ss_in,
    _Float16* __restrict__ fraw_h)
{
    __shared__ float ss[256], qq[256];
    int b = blockIdx.x;          // 64 blocks: k = b>>5, c = b&31
    int k = b >> 5, c = b & 31;
    int t = threadIdx.x;
    ss[t] = pIn[((size_t)k * 256 + t) * 64 + c];
    qq[t] = pIn[((size_t)k * 256 + t) * 64 + 32 + c];
    __syncthreads();
    if (t < 128) { ss[t] += ss[t + 128]; qq[t] += qq[t + 128]; } __syncthreads();
    if (t < 64)  { ss[t] += ss[t + 64];  qq[t] += qq[t + 64];  } __syncthreads();
    if (t < 32)  { ss[t] += ss[t + 32];  qq[t] += qq[t + 32];  } __syncthreads();
    if (t == 0) {
        float sv = 0.f, sq = 0.f;
#pragma unroll
        for (int i = 0; i < 32; ++i) { sv += ss[i]; sq += qq[i]; }
        float mu  = sv / (float)NPTS;
        float var = fmaxf(sq / (float)NPTS - mu * mu, 0.f);
        float rs  = rsqrtf(var + EPSV);
        float scale = g_in[k * 32 + c] * rs;
        float shift = b_in[k * 32 + c] - mu * scale;
        ss_in[k * 64 + c]      = scale;
        ss_in[k * 64 + 32 + c] = shift;
        float pad = (scale != 0.f) ? (-shift / scale) : 0.f;
        pad = fminf(fmaxf(pad, -60000.f), 60000.f);
        fraw_h[(size_t)k * (NPTS + 1) * 32 + c] = (_Float16)pad;   // row 0
    }
}

// L3: LEAN gather (BOTH k) + relu-max with COUNTED vmcnt pipeline (T4).
// 256 threads = 16 points x (4 jg x 4 chan-chunks). 5 packed vm loads/lane.
__global__ __launch_bounds__(256) void k_gather(
    const int* __restrict__ nc, const short* __restrict__ vm16,
    const _Float16* __restrict__ fraw_h, const float* __restrict__ pf,
    const float* __restrict__ ss_in, _Float16* __restrict__ nf_h)
{
    __shared__ __align__(16) _Float16 psum1[64 * 40];   // stride 40: conflict-free
    __shared__ __align__(16) _Float16 psum0[8 * 40];
    int t = threadIdx.x, bx = blockIdx.x;
    int c4 = t & 3, jg = (t >> 2) & 3, lp = t >> 4;
    int pt = bx * 16 + lp;

    // ---- scale vectors FIRST so the VMEM queue beyond this point is ours
    h8v sc1v, sc0v;
#pragma unroll
    for (int i = 0; i < 8; ++i) {
        sc1v[i] = (_Float16)ss_in[64 + c4 * 8 + i];
        sc0v[i] = (_Float16)ss_in[c4 * 8 + i];
    }
    // ---- coords + packed vm addresses
    int4 cc = ((const int4*)nc)[pt];
    int bb = cc.x, xc = cc.y, yc = cc.z, zc = cc.w;
    // reference quirk: fastest mesh idx -> z coord, slowest -> x coord
    int Zo[4];
#pragma unroll
    for (int u = 0; u < 4; ++u) {
        int zq = min(max(zc + u - 2, 0), ZD - 1);
        Zo[u] = (bb * ZD + zq) * (YD * XD);
    }
    int Yo1 = min(max(yc + jg - 2, 0), YD - 1) * XD;
    int ax1 = (min(max(xc - 2, 0), XD - 4)) & ~1;       // pack base (even)
    int Xoff[4];
#pragma unroll
    for (int a = 0; a < 4; ++a)
        Xoff[a] = min(max(xc - 2 + a, 0), XD - 1) - ax1;   // in [0,4]
    int zq0 = min(max(zc + (jg & 1) - 1, 0), ZD - 1);
    int yo0 = min(max(yc + (jg >> 1) - 1, 0), YD - 1) * XD;
    int zo0 = (bb * ZD + zq0) * (YD * XD);
    int x0a = min(max(xc - 1, 0), XD - 1);
    int x0b = min(max(xc, 0), XD - 1);
    int ax0 = x0a & ~1;
    int X0a = x0a - ax0, X0b = x0b - ax0;               // in [0,2]
    __builtin_amdgcn_sched_barrier(0);   // pin sc loads + addr calc above

    // ---- phase A: 5 packed vm loads in flight
    uint4 pk[4];
#pragma unroll
    for (int u = 0; u < 4; ++u)
        pk[u] = gload_u128(vm16 + Zo[u] + Yo1 + ax1);
    uint2 pk0 = gload_u64(vm16 + zo0 + yo0 + ax0);

    // ---- LDS staging (independent of phase A; also drains the sc loads)
    for (int i = t; i < 2048; i += 256) {
        int o = i >> 5, ch = i & 31;
        psum1[o * 40 + ch] = (_Float16)(pf[256 + i] + ss_in[96 + ch]);
    }
    {
        int o = t >> 5, ch = t & 31;
        psum0[o * 40 + ch] = (_Float16)(pf[t] + ss_in[32 + ch]);
    }
    __syncthreads();
    VM_WAIT(0);                          // packs (and everything prior) ready

    // ---- phase B: extract rows (pre-biased, no +1), issue 18 gathers in order
    const _Float16* fr1 = fraw_h + (size_t)(NPTS + 1) * 32;
    h8v g1[16], g0[2];
#pragma unroll
    for (int u = 0; u < 4; ++u) {
        unsigned long long lo = (unsigned long long)pk[u].x | ((unsigned long long)pk[u].y << 32);
        unsigned long long hi = (unsigned long long)pk[u].z | ((unsigned long long)pk[u].w << 32);
#pragma unroll
        for (int a = 0; a < 4; ++a) {
            int off = Xoff[a];
            unsigned long long sel = (off & 4) ? hi : lo;
            unsigned row = (unsigned)(sel >> ((off & 3) * 16)) & 0xFFFFu;
            g1[u * 4 + a] = gload_h8(fr1 + (size_t)row * 32 + c4 * 8);
        }
    }
    {
        unsigned long long l0 = (unsigned long long)pk0.x | ((unsigned long long)pk0.y << 32);
        unsigned r0 = (unsigned)(l0 >> (X0a * 16)) & 0xFFFFu;
        unsigned r1 = (unsigned)(l0 >> (X0b * 16)) & 0xFFFFu;
        g0[0] = gload_h8(fraw_h + (size_t)r0 * 32 + c4 * 8);
        g0[1] = gload_h8(fraw_h + (size_t)r1 * 32 + c4 * 8);
    }

    // ---- phase C: COUNTED-WAIT chunks — FMA overlaps the in-flight tail
    h8v acc1 = zero8(), acc0 = zero8();
    VM_WAIT(14);
#pragma unroll
    for (int i = 0; i < 4; ++i) {
        int o = (i & 3) * 16 + jg * 4 + (i >> 2);
        h8v pv = *(const h8v*)(psum1 + o * 40 + c4 * 8);
        acc1 = __builtin_elementwise_max(acc1, g1[i] * sc1v + pv);
    }
    VM_WAIT(10);
#pragma unroll
    for (int i = 4; i < 8; ++i) {
        int o = (i & 3) * 16 + jg * 4 + (i >> 2);
        h8v pv = *(const h8v*)(psum1 + o * 40 + c4 * 8);
        acc1 = __builtin_elementwise_max(acc1, g1[i] * sc1v + pv);
    }
    VM_WAIT(6);
#pragma unroll
    for (int i = 8; i < 12; ++i) {
        int o = (i & 3) * 16 + jg * 4 + (i >> 2);
        h8v pv = *(const h8v*)(psum1 + o * 40 + c4 * 8);
        acc1 = __builtin_elementwise_max(acc1, g1[i] * sc1v + pv);
    }
    VM_WAIT(2);
#pragma unroll
    for (int i = 12; i < 16; ++i) {
        int o = (i & 3) * 16 + jg * 4 + (i >> 2);
        h8v pv = *(const h8v*)(psum1 + o * 40 + c4 * 8);
        acc1 = __builtin_elementwise_max(acc1, g1[i] * sc1v + pv);
    }
    VM_WAIT(0);
    {
        h8v pv = *(const h8v*)(psum0 + jg * 40 + c4 * 8);
        acc0 = __builtin_elementwise_max(acc0, g0[0] * sc0v + pv);
        h8v pv2 = *(const h8v*)(psum0 + (4 + jg) * 40 + c4 * 8);
        acc0 = __builtin_elementwise_max(acc0, g0[1] * sc0v + pv2);
    }
    acc1 = __builtin_elementwise_max(acc1, shfl_xor_h8(acc1, 4));
    acc1 = __builtin_elementwise_max(acc1, shfl_xor_h8(acc1, 8));
    acc0 = __builtin_elementwise_max(acc0, shfl_xor_h8(acc0, 4));
    acc0 = __builtin_elementwise_max(acc0, shfl_xor_h8(acc0, 8));
    if (jg == 0) {
        *(h8v*)(nf_h + ((size_t)MGRID + pt) * 32 + c4 * 8) = acc1;   // k=1
        *(h8v*)(nf_h + (size_t)pt * 32 + c4 * 8) = acc0;             // k=0
    }
}

// L4: out-matmul stats partials; 128 points/block, grid (512, 2)
__global__ __launch_bounds__(256) void k_out_stats(
    const _Float16* __restrict__ nf_h, const float* __restrict__ Wout,
    float* __restrict__ pOut)
{
    __shared__ __align__(16) _Float16 nfs[128 * 32];   // 8 KB
    __shared__ h2 Wh[64 * 17];                          // 4.3 KB
    __shared__ float s_[256], q_[256];
    int k = blockIdx.y, t = threadIdx.x, bx = blockIdx.x;
    const _Float16* src = nf_h + ((size_t)k * MGRID + (size_t)bx * 128) * 32;
    ((uint4*)nfs)[t]       = ((const uint4*)src)[t];
    ((uint4*)nfs)[256 + t] = ((const uint4*)src)[256 + t];
    for (int i = t; i < 1024; i += 256) {
        int c = i >> 4, q = i & 15;
        h2 v;
        v.x = (_Float16)Wout[k * 2048 + c * 32 + 2 * q];
        v.y = (_Float16)Wout[k * 2048 + c * 32 + 2 * q + 1];
        Wh[c * 17 + q] = v;
    }
    __syncthreads();
    int c = t & 63, pg = t >> 6;
    h2 w[16];
#pragma unroll
    for (int i = 0; i < 16; ++i) w[i] = Wh[c * 17 + i];
    float sum = 0.f, sq = 0.f;
    for (int i = 0; i < 32; ++i) {
        const h2* row = (const h2*)(nfs + (pg * 32 + i) * 32);
        float y = 0.f;
#pragma unroll
        for (int iq = 0; iq < 16; ++iq) y = FDOT2(row[iq], w[iq], y);
        sum += y; sq += y * y;
    }
    s_[t] = sum; q_[t] = sq;
    __syncthreads();
    if (t < 128) { s_[t] += s_[t + 128]; q_[t] += q_[t + 128]; }
    __syncthreads();
    if (t < 64) {
        pOut[((size_t)k * 512 + bx) * 128 + t]      = s_[t] + s_[t + 64];
        pOut[((size_t)k * 512 + bx) * 128 + 64 + t] = q_[t] + q_[t + 64];
    }
}

// L5: parallel reduce pOut -> scale/shift ; one block per (k, c)
__global__ __launch_bounds__(256) void k_out_reduce(
    const float* __restrict__ pOut, const float* __restrict__ g_out,
    const float* __restrict__ b_out, float* __restrict__ ss_out)
{
    __shared__ float ss[256], qq[256];
    int b = blockIdx.x;          // 128 blocks: k = b>>6, c = b&63
    int k = b >> 6, c = b & 63;
    int t = threadIdx.x;
    float sv = 0.f, sq = 0.f;
#pragma unroll
    for (int i = 0; i < 2; ++i) {
        size_t row = (size_t)k * 512 + t + i * 256;
        sv += pOut[row * 128 + c];
        sq += pOut[row * 128 + 64 + c];
    }
    ss[t] = sv; qq[t] = sq;
    __syncthreads();
    if (t < 128) { ss[t] += ss[t + 128]; qq[t] += qq[t + 128]; } __syncthreads();
    if (t < 64)  { ss[t] += ss[t + 64];  qq[t] += qq[t + 64];  } __syncthreads();
    if (t < 32)  { ss[t] += ss[t + 32];  qq[t] += qq[t + 32];  } __syncthreads();
    if (t == 0) {
        float fs = 0.f, fq = 0.f;
#pragma unroll
        for (int i = 0; i < 32; ++i) { fs += ss[i]; fq += qq[i]; }
        float mu  = fs / (float)MGRID;
        float var = fmaxf(fq / (float)MGRID - mu * mu, 0.f);
        float rs  = rsqrtf(var + EPSV);
        float scale = g_out[k * 64 + c] * rs;
        float shift = b_out[k * 64 + c] - mu * scale;
        ss_out[k * 128 + c]      = scale;
        ss_out[k * 128 + 64 + c] = shift;
    }
}

// L6: out[:, k*64+c] = relu(y*scale + shift), dot2 matmul
__global__ __launch_bounds__(256) void k_out_write(
    const _Float16* __restrict__ nf_h, const float* __restrict__ Wout,
    const float* __restrict__ ss_out, float* __restrict__ out)
{
    __shared__ h2 Wh[64 * 17];
    int k = blockIdx.y, t = threadIdx.x;
    for (int i = t; i < 1024; i += 256) {
        int c = i >> 4, q = i & 15;
        h2 v;
        v.x = (_Float16)Wout[k * 2048 + c * 32 + 2 * q];
        v.y = (_Float16)Wout[k * 2048 + c * 32 + 2 * q + 1];
        Wh[c * 17 + q] = v;
    }
    __syncthreads();
    int c = t & 63, pl = t >> 6;
    float scale = ss_out[k * 128 + c], shift = ss_out[k * 128 + 64 + c];
    const h2* w = &Wh[c * 17];
    int base = blockIdx.x * 64;
    for (int it = 0; it < 16; ++it) {
        int pt = base + it * 4 + pl;
        const H8* row = (const H8*)(nf_h + ((size_t)k * MGRID + pt) * 32);
        H8 r0 = row[0], r1 = row[1], r2 = row[2], r3 = row[3];
        h2 hh[16] = {r0.a, r0.b, r0.c, r0.d, r1.a, r1.b, r1.c, r1.d,
                     r2.a, r2.b, r2.c, r2.d, r3.a, r3.b, r3.c, r3.d};
        float y = 0.f;
#pragma unroll
        for (int iq = 0; iq < 16; ++iq) y = FDOT2(hh[iq], w[iq], y);
        float o = y * scale + shift;
        out[(size_t)pt * 128 + k * 64 + c] = o > 0.f ? o : 0.f;
    }
}

extern "C" void kernel_launch(void* const* d_in, const int* in_sizes, int n_in,
                              void* d_out, int out_size, void* d_ws, size_t ws_size,
                              hipStream_t stream) {
    const int*   new_coords = (const int*)d_in[4];
    const float* features   = (const float*)d_in[5];
    const int*   vm         = (const int*)d_in[6];
    const float* W_in  = (const float*)d_in[7];
    const float* g_in  = (const float*)d_in[8];
    const float* b_in  = (const float*)d_in[9];
    const float* W_pos = (const float*)d_in[10];
    const float* g_pos = (const float*)d_in[11];
    const float* b_pos = (const float*)d_in[12];
    const float* W_out = (const float*)d_in[13];
    const float* g_out = (const float*)d_in[14];
    const float* b_out = (const float*)d_in[15];
    float* out = (float*)d_out;

    char* ws = (char*)d_ws;
    float*     ss_in  = (float*)(ws);
    float*     ss_out = (float*)(ws + 4096);
    float*     pIn    = (float*)(ws + 8192);
    _Float16*  fraw_h = (_Float16*)(ws + 139264);
    float*     pf     = (float*)(ws + 2236544);
    short*     vm16   = (short*)(ws + 2245760);
    _Float16*  nf_h   = (_Float16*)(ws + 3794560);
    float*     pOut   = (float*)(ws + 12183168);

    k_pre<<<NB_VM + 512 + 1, 256, 0, stream>>>(vm, features, W_in, W_pos, g_pos, b_pos,
                                               vm16, fraw_h, pIn, pf);
    k_reduce_in<<<64, 256, 0, stream>>>(pIn, g_in, b_in, ss_in, fraw_h);

    k_gather<<<MGRID / 16, 256, 0, stream>>>(new_coords, vm16, fraw_h, pf, ss_in, nf_h);

    dim3 gS(512, 2);
    k_out_stats<<<gS, 256, 0, stream>>>(nf_h, W_out, pOut);

    k_out_reduce<<<128, 256, 0, stream>>>(pOut, g_out, b_out, ss_out);

    dim3 gW(MGRID / 64, 2);
    k_out_write<<<gW, 256, 0, stream>>>(nf_h, W_out, ss_out, out);
}